// Round 2
// baseline (133.133 us; speedup 1.0000x reference)
//
#include <hip/hip_runtime.h>

#define NPTS 65536
#define NB_SHIFT 16   // log2(NPTS)
#define HID 64

// native vector types (HIP's float4/int4 are classes; the nontemporal
// builtins need real vector types)
typedef float vfloat4 __attribute__((ext_vector_type(4)));
typedef int   vint4   __attribute__((ext_vector_type(4)));

// ---------------- pre-pass: pos (B,3,N) -> xyzt (B,N) float4 ----------------
__global__ __launch_bounds__(256) void xyzt_kernel(const float* __restrict__ pos,
                                                   vfloat4* __restrict__ xyzt) {
    int g = blockIdx.x * 256 + threadIdx.x;          // 0 .. B*N-1
    int b = g >> NB_SHIFT;
    int n = g & (NPTS - 1);
    const float* p = pos + (size_t)b * 3 * NPTS;
    vfloat4 v;
    v.x = p[n];
    v.y = p[n + NPTS];
    v.z = p[n + 2 * NPTS];
    v.w = 0.f;
    // normal (cached) store: the main kernel re-reads this from L2
    xyzt[((size_t)b << NB_SHIFT) + n] = v;
}

// ---------------- main kernel ----------------
template <int USE_T>
__global__ __launch_bounds__(256, 4) void point_embed_kernel(
    const float*   __restrict__ pos,
    const vfloat4* __restrict__ xyzt,
    const int*     __restrict__ idx,
    const float*   __restrict__ dist,
    const float*   __restrict__ W,
    const float*   __restrict__ bias,
    float*         __restrict__ out) {
    // SoA layout: feat[c][point] -> phase-1 writes stride-1 across lanes
    // (conflict-free), phase-2 reads are 4-address broadcasts (conflict-free).
    __shared__ float featS[10][256];
    const int tid = threadIdx.x;

    // XCD-aware swizzle: blocks blockIdx%8==k run on XCD k and cover a
    // contiguous half-batch => gather working set per XCD = 1 MB (fits 4 MB L2).
    const int blk = ((int)blockIdx.x & 7) * 128 + ((int)blockIdx.x >> 3);
    const int g = blk * 256 + tid;                    // global point id
    const int b = g >> NB_SHIFT;
    const int n = g & (NPTS - 1);

    // --- phase 1: per-point feature (10 floats) ---
    // idx / dist are read exactly once -> nontemporal so they don't evict
    // the gather table from L2.
    const vint4* iv = (const vint4*)idx + (size_t)g * 4;
    vint4 i0 = __builtin_nontemporal_load(iv + 0);
    vint4 i1 = __builtin_nontemporal_load(iv + 1);
    vint4 i2 = __builtin_nontemporal_load(iv + 2);
    vint4 i3 = __builtin_nontemporal_load(iv + 3);
    const vfloat4* dv = (const vfloat4*)dist + (size_t)g * 4;
    vfloat4 d0 = __builtin_nontemporal_load(dv + 0);
    vfloat4 d1 = __builtin_nontemporal_load(dv + 1);
    vfloat4 d2 = __builtin_nontemporal_load(dv + 2);
    vfloat4 d3 = __builtin_nontemporal_load(dv + 3);
    float maxd = fmaxf(
        fmaxf(fmaxf(fmaxf(d0.x, d0.y), fmaxf(d0.z, d0.w)),
              fmaxf(fmaxf(d1.x, d1.y), fmaxf(d1.z, d1.w))),
        fmaxf(fmaxf(fmaxf(d2.x, d2.y), fmaxf(d2.z, d2.w)),
              fmaxf(fmaxf(d3.x, d3.y), fmaxf(d3.z, d3.w))));

    float cx, cy, cz;
    float mxx = -INFINITY, mxy = -INFINITY, mxz = -INFINITY;
    float mnx = INFINITY, mny = INFINITY, mnz = INFINITY;

    if (USE_T) {
        const vfloat4* xb = xyzt + ((size_t)b << NB_SHIFT);
        vfloat4 c = xb[n];                // coalesced; L2-cached table
        cx = c.x; cy = c.y; cz = c.z;
#define GATH(J)                                   \
    {                                             \
        vfloat4 q = xb[(unsigned)(J)];            \
        mxx = fmaxf(mxx, q.x);                    \
        mxy = fmaxf(mxy, q.y);                    \
        mxz = fmaxf(mxz, q.z);                    \
        mnx = fminf(mnx, q.x);                    \
        mny = fminf(mny, q.y);                    \
        mnz = fminf(mnz, q.z);                    \
    }
        GATH(i0.x) GATH(i0.y) GATH(i0.z) GATH(i0.w)
        GATH(i1.x) GATH(i1.y) GATH(i1.z) GATH(i1.w)
        GATH(i2.x) GATH(i2.y) GATH(i2.z) GATH(i2.w)
        GATH(i3.x) GATH(i3.y) GATH(i3.z) GATH(i3.w)
#undef GATH
    } else {
        const float* px = pos + (size_t)b * 3 * NPTS;
        cx = px[n]; cy = px[n + NPTS]; cz = px[n + 2 * NPTS];
#define GATH(J)                                   \
    {                                             \
        float qx = px[(unsigned)(J)];             \
        float qy = px[(unsigned)(J) + NPTS];      \
        float qz = px[(unsigned)(J) + 2 * NPTS];  \
        mxx = fmaxf(mxx, qx);                     \
        mxy = fmaxf(mxy, qy);                     \
        mxz = fmaxf(mxz, qz);                     \
        mnx = fminf(mnx, qx);                     \
        mny = fminf(mny, qy);                     \
        mnz = fminf(mnz, qz);                     \
    }
        GATH(i0.x) GATH(i0.y) GATH(i0.z) GATH(i0.w)
        GATH(i1.x) GATH(i1.y) GATH(i1.z) GATH(i1.w)
        GATH(i2.x) GATH(i2.y) GATH(i2.z) GATH(i2.w)
        GATH(i3.x) GATH(i3.y) GATH(i3.z) GATH(i3.w)
#undef GATH
    }

    featS[0][tid] = cx;
    featS[1][tid] = cy;
    featS[2][tid] = cz;
    featS[3][tid] = mxx;
    featS[4][tid] = mxy;
    featS[5][tid] = mxz;
    featS[6][tid] = cx - mnx;
    featS[7][tid] = cy - mny;
    featS[8][tid] = cz - mnz;
    featS[9][tid] = maxd;

    // W/bias loads issued here (after gathers retire -> low peak VGPR,
    // overlap with the barrier wait). Tiny + shared by all blocks -> L2-hot.
    const int hq = tid & 15;
    vfloat4 Wv[10];
#pragma unroll
    for (int c = 0; c < 10; ++c)
        Wv[c] = ((const vfloat4*)(W + c * HID))[hq];
    vfloat4 bv = ((const vfloat4*)bias)[hq];

    __syncthreads();

    // --- phase 2: 256 points x 64 hidden, coalesced nontemporal stores ---
    const int prow = tid >> 4;                       // 0..15
    const size_t outbase = (size_t)blk * 256 * HID;
#pragma unroll
    for (int i = 0; i < 16; ++i) {
        const int p = i * 16 + prow;
        vfloat4 acc = bv;
#pragma unroll
        for (int c = 0; c < 10; ++c) {
            const float fv = featS[c][p];
            acc.x += fv * Wv[c].x;
            acc.y += fv * Wv[c].y;
            acc.z += fv * Wv[c].z;
            acc.w += fv * Wv[c].w;
        }
        acc.x = fmaxf(acc.x, 0.f);
        acc.y = fmaxf(acc.y, 0.f);
        acc.z = fmaxf(acc.z, 0.f);
        acc.w = fmaxf(acc.w, 0.f);
        __builtin_nontemporal_store(
            acc, (vfloat4*)(out + outbase + (size_t)p * HID) + hq);
    }
}

extern "C" void kernel_launch(void* const* d_in, const int* in_sizes, int n_in,
                              void* d_out, int out_size, void* d_ws, size_t ws_size,
                              hipStream_t stream) {
    const float* pos  = (const float*)d_in[0];
    const int*   idx  = (const int*)d_in[1];
    const float* dist = (const float*)d_in[2];
    const float* W    = (const float*)d_in[3];
    const float* bias = (const float*)d_in[4];
    float* out = (float*)d_out;

    const int total   = in_sizes[0] / 3;     // B*N = 262144
    const int nblocks = total / 256;         // 1024
    const size_t need = (size_t)total * sizeof(vfloat4);  // 16 MB

    if (ws_size >= need) {
        xyzt_kernel<<<nblocks, 256, 0, stream>>>(pos, (vfloat4*)d_ws);
        point_embed_kernel<1><<<nblocks, 256, 0, stream>>>(
            pos, (const vfloat4*)d_ws, idx, dist, W, bias, out);
    } else {
        point_embed_kernel<0><<<nblocks, 256, 0, stream>>>(
            pos, nullptr, idx, dist, W, bias, out);
    }
}

// Round 3
// 122.109 us; speedup vs baseline: 1.0903x; 1.0903x over previous
//
#include <hip/hip_runtime.h>

#define NPTS 65536
#define NB_SHIFT 16   // log2(NPTS)
#define HID 64

typedef float vfloat4 __attribute__((ext_vector_type(4)));
typedef int   vint4   __attribute__((ext_vector_type(4)));

// ---------------- pre-pass: pos (B,3,N) -> xyzt (B,N) float4 ----------------
__global__ __launch_bounds__(256) void xyzt_kernel(const float* __restrict__ pos,
                                                   vfloat4* __restrict__ xyzt) {
    int g = blockIdx.x * 256 + threadIdx.x;          // 0 .. B*N-1
    int b = g >> NB_SHIFT;
    int n = g & (NPTS - 1);
    const float* p = pos + (size_t)b * 3 * NPTS;
    vfloat4 v;
    v.x = p[n];
    v.y = p[n + NPTS];
    v.z = p[n + 2 * NPTS];
    v.w = 0.f;
    xyzt[((size_t)b << NB_SHIFT) + n] = v;
}

// ---------------- main kernel ----------------
template <int USE_T>
__global__ __launch_bounds__(256, 4) void point_embed_kernel(
    const float*   __restrict__ pos,
    const vfloat4* __restrict__ xyzt,
    const int*     __restrict__ idx,
    const float*   __restrict__ dist,
    const float*   __restrict__ W,
    const float*   __restrict__ bias,
    float*         __restrict__ out) {
    // SoA: phase-1 writes stride-1, phase-2 reads broadcast -> conflict-free
    __shared__ float featS[10][256];
    const int tid = threadIdx.x;

    // XCD-aware swizzle: each XCD's gather window = one batch's 1 MB table
    const int blk = ((int)blockIdx.x & 7) * 128 + ((int)blockIdx.x >> 3);
    const int g = blk * 256 + tid;                    // global point id
    const int b = g >> NB_SHIFT;
    const int n = g & (NPTS - 1);

    // --- phase 1: indices first, then ALL 16 gathers issued back-to-back ---
    const vint4* iv = (const vint4*)idx + (size_t)g * 4;
    vint4 i0 = iv[0], i1 = iv[1], i2 = iv[2], i3 = iv[3];

    float cx, cy, cz;
    float mxx = -INFINITY, mxy = -INFINITY, mxz = -INFINITY;
    float mnx = INFINITY, mny = INFINITY, mnz = INFINITY;
    float maxd;

    if (USE_T) {
        const vfloat4* xb = xyzt + ((size_t)b << NB_SHIFT);
        vfloat4 c = xb[n];
        // all 16 gathers live simultaneously (q[16] = 64 VGPRs; budget 128
        // via __launch_bounds__(256,4) — occupancy is grid-capped anyway)
        vfloat4 q[16];
        q[0]  = xb[(unsigned)i0.x];
        q[1]  = xb[(unsigned)i0.y];
        q[2]  = xb[(unsigned)i0.z];
        q[3]  = xb[(unsigned)i0.w];
        q[4]  = xb[(unsigned)i1.x];
        q[5]  = xb[(unsigned)i1.y];
        q[6]  = xb[(unsigned)i1.z];
        q[7]  = xb[(unsigned)i1.w];
        q[8]  = xb[(unsigned)i2.x];
        q[9]  = xb[(unsigned)i2.y];
        q[10] = xb[(unsigned)i2.z];
        q[11] = xb[(unsigned)i2.w];
        q[12] = xb[(unsigned)i3.x];
        q[13] = xb[(unsigned)i3.y];
        q[14] = xb[(unsigned)i3.z];
        q[15] = xb[(unsigned)i3.w];

        // dist load + reduce overlaps the in-flight gathers
        const vfloat4* dv = (const vfloat4*)dist + (size_t)g * 4;
        vfloat4 d0 = dv[0], d1 = dv[1], d2 = dv[2], d3 = dv[3];
        maxd = fmaxf(
            fmaxf(fmaxf(fmaxf(d0.x, d0.y), fmaxf(d0.z, d0.w)),
                  fmaxf(fmaxf(d1.x, d1.y), fmaxf(d1.z, d1.w))),
            fmaxf(fmaxf(fmaxf(d2.x, d2.y), fmaxf(d2.z, d2.w)),
                  fmaxf(fmaxf(d3.x, d3.y), fmaxf(d3.z, d3.w))));

        cx = c.x; cy = c.y; cz = c.z;
#pragma unroll
        for (int j = 0; j < 16; ++j) {
            mxx = fmaxf(mxx, q[j].x);
            mxy = fmaxf(mxy, q[j].y);
            mxz = fmaxf(mxz, q[j].z);
            mnx = fminf(mnx, q[j].x);
            mny = fminf(mny, q[j].y);
            mnz = fminf(mnz, q[j].z);
        }
    } else {
        const float* px = pos + (size_t)b * 3 * NPTS;
        cx = px[n]; cy = px[n + NPTS]; cz = px[n + 2 * NPTS];
        const vfloat4* dv = (const vfloat4*)dist + (size_t)g * 4;
        vfloat4 d0 = dv[0], d1 = dv[1], d2 = dv[2], d3 = dv[3];
        maxd = fmaxf(
            fmaxf(fmaxf(fmaxf(d0.x, d0.y), fmaxf(d0.z, d0.w)),
                  fmaxf(fmaxf(d1.x, d1.y), fmaxf(d1.z, d1.w))),
            fmaxf(fmaxf(fmaxf(d2.x, d2.y), fmaxf(d2.z, d2.w)),
                  fmaxf(fmaxf(d3.x, d3.y), fmaxf(d3.z, d3.w))));
        int ids[16] = {i0.x, i0.y, i0.z, i0.w, i1.x, i1.y, i1.z, i1.w,
                       i2.x, i2.y, i2.z, i2.w, i3.x, i3.y, i3.z, i3.w};
#pragma unroll
        for (int j = 0; j < 16; ++j) {
            float qx = px[(unsigned)ids[j]];
            float qy = px[(unsigned)ids[j] + NPTS];
            float qz = px[(unsigned)ids[j] + 2 * NPTS];
            mxx = fmaxf(mxx, qx);
            mxy = fmaxf(mxy, qy);
            mxz = fmaxf(mxz, qz);
            mnx = fminf(mnx, qx);
            mny = fminf(mny, qy);
            mnz = fminf(mnz, qz);
        }
    }

    featS[0][tid] = cx;
    featS[1][tid] = cy;
    featS[2][tid] = cz;
    featS[3][tid] = mxx;
    featS[4][tid] = mxy;
    featS[5][tid] = mxz;
    featS[6][tid] = cx - mnx;
    featS[7][tid] = cy - mny;
    featS[8][tid] = cz - mnz;
    featS[9][tid] = maxd;

    // W/bias after the gather retires (low peak VGPR in the gather window)
    const int hq = tid & 15;
    vfloat4 Wv[10];
#pragma unroll
    for (int c = 0; c < 10; ++c)
        Wv[c] = ((const vfloat4*)(W + c * HID))[hq];
    vfloat4 bv = ((const vfloat4*)bias)[hq];

    __syncthreads();

    // --- phase 2: 256 points x 64 hidden, coalesced nontemporal stores ---
    const int prow = tid >> 4;                       // 0..15
    const size_t outbase = (size_t)blk * 256 * HID;
#pragma unroll
    for (int i = 0; i < 16; ++i) {
        const int p = i * 16 + prow;
        vfloat4 acc = bv;
#pragma unroll
        for (int c = 0; c < 10; ++c) {
            const float fv = featS[c][p];
            acc.x += fv * Wv[c].x;
            acc.y += fv * Wv[c].y;
            acc.z += fv * Wv[c].z;
            acc.w += fv * Wv[c].w;
        }
        acc.x = fmaxf(acc.x, 0.f);
        acc.y = fmaxf(acc.y, 0.f);
        acc.z = fmaxf(acc.z, 0.f);
        acc.w = fmaxf(acc.w, 0.f);
        __builtin_nontemporal_store(
            acc, (vfloat4*)(out + outbase + (size_t)p * HID) + hq);
    }
}

extern "C" void kernel_launch(void* const* d_in, const int* in_sizes, int n_in,
                              void* d_out, int out_size, void* d_ws, size_t ws_size,
                              hipStream_t stream) {
    const float* pos  = (const float*)d_in[0];
    const int*   idx  = (const int*)d_in[1];
    const float* dist = (const float*)d_in[2];
    const float* W    = (const float*)d_in[3];
    const float* bias = (const float*)d_in[4];
    float* out = (float*)d_out;

    const int total   = in_sizes[0] / 3;     // B*N = 262144
    const int nblocks = total / 256;         // 1024
    const size_t need = (size_t)total * sizeof(vfloat4);  // 16 MB

    if (ws_size >= need) {
        xyzt_kernel<<<nblocks, 256, 0, stream>>>(pos, (vfloat4*)d_ws);
        point_embed_kernel<1><<<nblocks, 256, 0, stream>>>(
            pos, (const vfloat4*)d_ws, idx, dist, W, bias, out);
    } else {
        point_embed_kernel<0><<<nblocks, 256, 0, stream>>>(
            pos, nullptr, idx, dist, W, bias, out);
    }
}